// Round 16
// baseline (525.908 us; speedup 1.0000x reference)
//
#include <hip/hip_runtime.h>
#include <math.h>

// B=4, C=512, n=1024 tokens, 16 heads x dh=32, 4 layers, GEGLU dff=2048.
// Residual stream fp32; GEMMs + attention bf16 MFMA (16x16x32), fp32 accum.
// r15 base (513us) + TM=64 for ff1 and QKV (3 blocks/CU occupancy).

typedef __bf16 bf16x8_t __attribute__((ext_vector_type(8)));
typedef float f32x4 __attribute__((ext_vector_type(4)));

__device__ __forceinline__ unsigned short f2bf(float f) {
  unsigned u = __float_as_uint(f);
  return (unsigned short)((u + 0x7FFFu + ((u >> 16) & 1u)) >> 16);
}
__device__ __forceinline__ float gelu_exact(float x) {
  return 0.5f * x * (1.f + erff(x * 0.70710678118654752440f));
}

// -------- GroupNorm stats: per (b,g) mean/rstd -> per-channel scale/shift ---
__global__ __launch_bounds__(256) void gn_stats(
    const float* __restrict__ X, const float* __restrict__ w,
    const float* __restrict__ b, float* __restrict__ sc,
    float* __restrict__ sh) {
  int blk = blockIdx.x;  // b*16 + g
  int g = blk & 15, bb = blk >> 4;
  const float4* x4 = (const float4*)(X + (size_t)blk * 32768);
  int tid = threadIdx.x;
  float sum = 0.f, sq = 0.f;
  for (int i = tid; i < 8192; i += 256) {
    float4 v = x4[i];
    sum += v.x + v.y + v.z + v.w;
    sq += v.x * v.x + v.y * v.y + v.z * v.z + v.w * v.w;
  }
  #pragma unroll
  for (int off = 32; off; off >>= 1) {
    sum += __shfl_xor(sum, off);
    sq += __shfl_xor(sq, off);
  }
  __shared__ float s0[4], s1[4];
  int wid = tid >> 6, lane = tid & 63;
  if (lane == 0) { s0[wid] = sum; s1[wid] = sq; }
  __syncthreads();
  sum = s0[0] + s0[1] + s0[2] + s0[3];
  sq = s1[0] + s1[1] + s1[2] + s1[3];
  float mean = sum * (1.f / 32768.f);
  float var = sq * (1.f / 32768.f) - mean * mean;
  float rstd = rsqrtf(var + 1e-6f);
  if (tid < 32) {
    int ch = g * 32 + tid;
    float s_ = rstd * w[ch];
    sc[bb * 512 + ch] = s_;
    sh[bb * 512 + ch] = b[ch] - mean * s_;
  }
}

// ------- batched transpose+convert: fp32 [rows][cols] -> bf16 [cols][rows] --
struct CvtEnt {
  const float* src; unsigned short* dst;
  const float* rs; const float* rsh;
  int rows, cols, nmat, pre; float scale; size_t mstr;
};
struct CvtTab { CvtEnt e[9]; };

__global__ __launch_bounds__(256) void cvt_all(CvtTab tab) {
  __shared__ __bf16 t[32][72];
  int blk = blockIdx.x;
  int ei = 0;
  #pragma unroll
  for (int i = 1; i < 9; ++i)
    if (blk >= tab.e[i].pre) ei = i;
  const CvtEnt E = tab.e[ei];
  int local = blk - E.pre;
  int tcx = E.cols >> 5, trx = E.rows >> 6;
  int tpm = tcx * trx;
  int mat = local / tpm, tt = local - mat * tpm;
  int r0 = (tt / tcx) << 6, c0 = (tt % tcx) << 5;
  const float* sp = E.src + (size_t)mat * E.rows * E.cols;
  unsigned short* dp = E.dst + (size_t)mat * E.mstr;
  int tid = threadIdx.x;
  int r = tid >> 2, cq = (tid & 3) << 3;
  float s_ = E.scale, h_ = 0.f;
  if (E.rs) {
    s_ = E.rs[(size_t)mat * E.rows + r0 + r];
    h_ = E.rsh[(size_t)mat * E.rows + r0 + r];
  }
  const float* rowp = sp + (size_t)(r0 + r) * E.cols + c0 + cq;
  float4 a = *(const float4*)rowp;
  float4 b = *(const float4*)(rowp + 4);
  t[cq + 0][r] = (__bf16)(a.x * s_ + h_);
  t[cq + 1][r] = (__bf16)(a.y * s_ + h_);
  t[cq + 2][r] = (__bf16)(a.z * s_ + h_);
  t[cq + 3][r] = (__bf16)(a.w * s_ + h_);
  t[cq + 4][r] = (__bf16)(b.x * s_ + h_);
  t[cq + 5][r] = (__bf16)(b.y * s_ + h_);
  t[cq + 6][r] = (__bf16)(b.z * s_ + h_);
  t[cq + 7][r] = (__bf16)(b.w * s_ + h_);
  __syncthreads();
  int c = tid >> 3, r8 = (tid & 7) << 3;
  bf16x8_t v = *(const bf16x8_t*)&t[c][r8];
  *(bf16x8_t*)&dp[(size_t)(c0 + c) * E.rows + r0 + r8] = v;
}

// -------- LayerNorm C=512: wave per row, 4 rows/block, fp32->bf16 ---------
__global__ __launch_bounds__(256) void ln_kernel(
    const float* __restrict__ X, const float* __restrict__ w,
    const float* __restrict__ b, unsigned short* __restrict__ Y) {
  int row = blockIdx.x * 4 + (threadIdx.x >> 6);
  int lane = threadIdx.x & 63;
  const float4* xr = (const float4*)(X + (size_t)row * 512);
  float4 v0 = xr[lane];
  float4 v1 = xr[lane + 64];
  float sum = v0.x + v0.y + v0.z + v0.w + v1.x + v1.y + v1.z + v1.w;
  float sq = v0.x * v0.x + v0.y * v0.y + v0.z * v0.z + v0.w * v0.w +
             v1.x * v1.x + v1.y * v1.y + v1.z * v1.z + v1.w * v1.w;
  #pragma unroll
  for (int off = 32; off; off >>= 1) {
    sum += __shfl_xor(sum, off);
    sq += __shfl_xor(sq, off);
  }
  float mean = sum * (1.f / 512.f);
  float var = sq * (1.f / 512.f) - mean * mean;
  float rstd = rsqrtf(var + 1e-5f);
  unsigned short* yr = Y + (size_t)row * 512;
  int c0 = lane * 4, c1 = lane * 4 + 256;
  const float4 w0 = *(const float4*)&w[c0], b0v = *(const float4*)&b[c0];
  const float4 w1 = *(const float4*)&w[c1], b1v = *(const float4*)&b[c1];
  unsigned p0 = (unsigned)f2bf((v0.x - mean) * rstd * w0.x + b0v.x) |
                ((unsigned)f2bf((v0.y - mean) * rstd * w0.y + b0v.y) << 16);
  unsigned p1 = (unsigned)f2bf((v0.z - mean) * rstd * w0.z + b0v.z) |
                ((unsigned)f2bf((v0.w - mean) * rstd * w0.w + b0v.w) << 16);
  unsigned p2 = (unsigned)f2bf((v1.x - mean) * rstd * w1.x + b1v.x) |
                ((unsigned)f2bf((v1.y - mean) * rstd * w1.y + b1v.y) << 16);
  unsigned p3 = (unsigned)f2bf((v1.z - mean) * rstd * w1.z + b1v.z) |
                ((unsigned)f2bf((v1.w - mean) * rstd * w1.w + b1v.w) << 16);
  uint2 q0 = {p0, p1}, q1 = {p2, p3};
  *(uint2*)&yr[c0] = q0;
  *(uint2*)&yr[c1] = q1;
}

// ---------------- bf16 MFMA GEMM (16x16x32, XCD-swizzled, reg-staged) ------
// A [M][lda] bf16 row-major; B^T [N][K] bf16 row-major.
// 256 thr = 4 waves (2x2), tile TM x TN, wave tile (TM/2)x(TN/2), BK=64.
// MODE 0: C_f32 = acc (+bias).
// MODE 1: v = acc+bias+resid -> C_f32 and Cb_bf16 (LDS-repacked write).
// MODE 2: GEGLU: Cb_bf16 = (acc+bias[col]) * gelu(acc2+bias[ggoff+col]).
// MODE 3: bf16 = acc -> C reinterpreted as bf16 (LDS-repacked write).
// MODE 4: out[b][col][n] = acc + bias[col] + resid[b][col][n] (rows = tokens).
// MODE 5: C_f32 = acc+bias+resid (no bf16 mirror).
template <int TM, int TN, int MODE>
__global__ __launch_bounds__(256) void mgemm(
    const short* __restrict__ A, int lda, const short* __restrict__ B0,
    float* C0, unsigned short* Cb, int ldc,
    const float* __restrict__ bias, const float* resid, int K, int ggoff) {
  constexpr int WM = TM / 2, WN = TN / 2, MF = WM / 16, NF = WN / 16;
  constexpr int ASL = TM / 32;
  constexpr int BSL = TN / 32;
  __shared__ short As[2][TM][64];
  __shared__ short Bs[2][TN][64];
  __shared__ short Bs2[MODE == 2 ? 2 : 1][MODE == 2 ? TN : 1][64];

  // ---- XCD-band swizzle (requires gridDim.y % 8 == 0) ----
  int flat = (blockIdx.z * gridDim.y + blockIdx.y) * gridDim.x + blockIdx.x;
  int xcd = flat & 7;
  int pos = flat >> 3;
  int bandH = gridDim.y >> 3;
  int m_loc = pos % bandH;
  int bn_i = pos / bandH;
  int bm = (xcd * bandH + m_loc) * TM;
  int bn = bn_i * TN;

  const short* B = B0;
  float* C = C0;
  const short* Bg = (MODE == 2) ? B0 + (size_t)ggoff * K : nullptr;
  unsigned short* Cbw = (MODE == 3) ? (unsigned short*)C : Cb;

  int tid = threadIdx.x;

  f32x4 acc[MF][NF];
  f32x4 acc2[MODE == 2 ? MF : 1][MODE == 2 ? NF : 1];
  #pragma unroll
  for (int m = 0; m < MF; ++m)
    #pragma unroll
    for (int n = 0; n < NF; ++n) {
      acc[m][n] = (f32x4)0.f;
      if (MODE == 2) acc2[m][n] = (f32x4)0.f;
    }

  int wid = tid >> 6, lane = tid & 63;
  int wr = wid >> 1, wc = wid & 1;
  int lrow = lane & 15, lhk = lane >> 4;

  bf16x8_t ra[ASL], rb[BSL], rb2[MODE == 2 ? BSL : 1];

  auto load_regs = [&](int k0) {
    #pragma unroll
    for (int i = 0; i < ASL; ++i) {
      int slot = tid + i * 256, r = slot >> 3, s = slot & 7;
      ra[i] = *(const bf16x8_t*)(A + (size_t)(bm + r) * lda + k0 + s * 8);
    }
    #pragma unroll
    for (int i = 0; i < BSL; ++i) {
      int slot = tid + i * 256, r = slot >> 3, s = slot & 7;
      rb[i] = *(const bf16x8_t*)(B + (size_t)(bn + r) * K + k0 + s * 8);
      if (MODE == 2)
        rb2[i] = *(const bf16x8_t*)(Bg + (size_t)(bn + r) * K + k0 + s * 8);
    }
  };
  auto store_lds = [&](int bufi) {
    #pragma unroll
    for (int i = 0; i < ASL; ++i) {
      int slot = tid + i * 256, r = slot >> 3, s = slot & 7;
      *(bf16x8_t*)&As[bufi][r][(s ^ (r & 7)) * 8] = ra[i];
    }
    #pragma unroll
    for (int i = 0; i < BSL; ++i) {
      int slot = tid + i * 256, r = slot >> 3, s = slot & 7;
      *(bf16x8_t*)&Bs[bufi][r][(s ^ (r & 7)) * 8] = rb[i];
      if (MODE == 2) *(bf16x8_t*)&Bs2[bufi][r][(s ^ (r & 7)) * 8] = rb2[i];
    }
  };
  auto compute = [&](int bufi) {
    bf16x8_t af[2][MF], bfr[2][NF], bf2[MODE == 2 ? 2 : 1][MODE == 2 ? NF : 1];
    #pragma unroll
    for (int ks = 0; ks < 2; ++ks) {
      int sl = ks * 4 + lhk;
      int ph = (sl ^ (lrow & 7)) * 8;
      #pragma unroll
      for (int m = 0; m < MF; ++m)
        af[ks][m] = *(const bf16x8_t*)&As[bufi][wr * WM + m * 16 + lrow][ph];
      #pragma unroll
      for (int n = 0; n < NF; ++n) {
        bfr[ks][n] = *(const bf16x8_t*)&Bs[bufi][wc * WN + n * 16 + lrow][ph];
        if (MODE == 2)
          bf2[ks][n] = *(const bf16x8_t*)&Bs2[bufi][wc * WN + n * 16 + lrow][ph];
      }
    }
    #pragma unroll
    for (int ks = 0; ks < 2; ++ks)
      #pragma unroll
      for (int m = 0; m < MF; ++m)
        #pragma unroll
        for (int n = 0; n < NF; ++n) {
          acc[m][n] = __builtin_amdgcn_mfma_f32_16x16x32_bf16(
              af[ks][m], bfr[ks][n], acc[m][n], 0, 0, 0);
          if (MODE == 2)
            acc2[m][n] = __builtin_amdgcn_mfma_f32_16x16x32_bf16(
                af[ks][m], bf2[ks][n], acc2[m][n], 0, 0, 0);
        }
  };

  int ns = K >> 6;
  load_regs(0);
  store_lds(0);
  __syncthreads();
  int buf = 0;
  for (int t = 0; t < ns; ++t) {
    bool more = (t + 1 < ns);
    if (more) load_regs((t + 1) << 6);  // issue early (T14)
    compute(buf);
    if (more) store_lds(buf ^ 1);       // write late
    __syncthreads();
    buf ^= 1;
  }

  int row0 = bm + wr * WM + lhk * 4;
  int col0 = bn + wc * WN + lrow;
  // LDS repack buffer for coalesced bf16 output (reuses As)
  unsigned short (*Lb)[TN] = (unsigned short(*)[TN])(&As[0][0][0]);
  #pragma unroll
  for (int m = 0; m < MF; ++m) {
    #pragma unroll
    for (int n = 0; n < NF; ++n) {
      int col = col0 + n * 16;
      int rl0 = wr * WM + m * 16 + lhk * 4;  // row within tile
      int cl = wc * WN + n * 16 + lrow;      // col within tile
      if (MODE == 0) {
        float bv = bias ? bias[col] : 0.f;
        #pragma unroll
        for (int j = 0; j < 4; ++j) {
          int row = row0 + m * 16 + j;
          C[(size_t)row * ldc + col] = acc[m][n][j] + bv;
        }
      } else if (MODE == 1) {
        float bv = bias[col];
        #pragma unroll
        for (int j = 0; j < 4; ++j) {
          int row = row0 + m * 16 + j;
          float v = acc[m][n][j] + bv + resid[(size_t)row * ldc + col];
          C[(size_t)row * ldc + col] = v;
          Lb[rl0 + j][cl] = f2bf(v);
        }
      } else if (MODE == 2) {
        float ba = bias[col], bg = bias[ggoff + col];
        #pragma unroll
        for (int j = 0; j < 4; ++j) {
          float a = acc[m][n][j] + ba;
          float g = acc2[m][n][j] + bg;
          Lb[rl0 + j][cl] = f2bf(a * gelu_exact(g));
        }
      } else if (MODE == 3) {
        #pragma unroll
        for (int j = 0; j < 4; ++j) Lb[rl0 + j][cl] = f2bf(acc[m][n][j]);
      } else if (MODE == 4) {
        // transposed write + bias + residual, rows = tokens
        float bv = bias[col];
        int row = row0 + m * 16;
        int b_ = row >> 10, n0 = row & 1023;
        size_t oidx = ((size_t)b_ * 512 + col) * 1024 + n0;
        float4 xi = *(const float4*)&resid[oidx];
        float4 ov = {acc[m][n][0] + bv + xi.x, acc[m][n][1] + bv + xi.y,
                     acc[m][n][2] + bv + xi.z, acc[m][n][3] + bv + xi.w};
        *(float4*)&C[oidx] = ov;
      } else {
        // MODE 5: fp32 bias+resid only
        float bv = bias[col];
        #pragma unroll
        for (int j = 0; j < 4; ++j) {
          int row = row0 + m * 16 + j;
          C[(size_t)row * ldc + col] =
              acc[m][n][j] + bv + resid[(size_t)row * ldc + col];
        }
      }
    }
  }
  if (MODE == 1 || MODE == 2 || MODE == 3) {
    __syncthreads();
    constexpr int CQ = TN / 8;
    #pragma unroll
    for (int i = 0; i < TM * TN / 8 / 256; ++i) {
      int slot = tid + i * 256;
      int r = slot / CQ, cq = (slot % CQ) * 8;
      *(bf16x8_t*)&Cbw[(size_t)(bm + r) * ldc + bn + cq] =
          *(const bf16x8_t*)&Lb[r][cq];
    }
  }
}

// ---------------- MFMA flash attention (QT=64, dbuf K/V, 1 barrier/tile) ---
// Block = (q-tile of 64, head, batch); 256 thr = 4 waves, wave owns 16 q.
// QKV packed [4096][1536] (q|k|v), Q pre-scaled by log2(e)/sqrt(32).
// Pitches (empirically best, r8): Ks 40, Vs 68, Ps 68.
__global__ __launch_bounds__(256) void fattn_kernel(
    const unsigned short* __restrict__ QKV, unsigned short* __restrict__ O) {
  constexpr int KT = 64, LDQ = 1536;
  __shared__ __bf16 Ks[2][KT][40];
  __shared__ __bf16 Vs[2][32][68];
  __shared__ __bf16 Ps[4][16][68];

  int h = blockIdx.y, bb = blockIdx.z;
  int q0 = blockIdx.x * 64;
  int tid = threadIdx.x;
  int wid = tid >> 6, lane = tid & 63;
  int lrow = lane & 15, lhk = lane >> 4;

  const unsigned short* Qb = QKV + (size_t)bb * 1024 * LDQ + h * 32;
  const unsigned short* Kb = Qb + 512;
  const unsigned short* Vb = Qb + 1024;

  bf16x8_t qa = *(const bf16x8_t*)(
      Qb + (size_t)(q0 + wid * 16 + lrow) * LDQ + lhk * 8);

  int kr = tid >> 2, kp = tid & 3;
  int vk = tid & 63, vd0 = (tid >> 6) * 8;

  bf16x8_t kreg, vreg;
  auto gload = [&](int kt) {
    kreg = *(const bf16x8_t*)(Kb + (size_t)(kt + kr) * LDQ + kp * 8);
    vreg = *(const bf16x8_t*)(Vb + (size_t)(kt + vk) * LDQ + vd0);
  };
  auto sstore = [&](int bufi) {
    *(bf16x8_t*)&Ks[bufi][kr][kp * 8] = kreg;
    #pragma unroll
    for (int i = 0; i < 8; ++i) Vs[bufi][vd0 + i][vk] = vreg[i];
  };

  f32x4 o[2];
  float lpart[4];
  o[0] = (f32x4)0.f;
  o[1] = (f32x4)0.f;
  #pragma unroll
  for (int j = 0; j < 4; ++j) lpart[j] = 0.f;

  gload(0);
  sstore(0);
  __syncthreads();
  for (int t = 0; t < 16; ++t) {
    int buf = t & 1;
    if (t < 15) gload((t + 1) * KT);  // prefetch next tile into regs (T14)

    bf16x8_t kb[4];
    #pragma unroll
    for (int n = 0; n < 4; ++n)
      kb[n] = *(const bf16x8_t*)&Ks[buf][n * 16 + lrow][lhk * 8];
    f32x4 s[4];
    __builtin_amdgcn_s_setprio(1);
    #pragma unroll
    for (int n = 0; n < 4; ++n)
      s[n] = __builtin_amdgcn_mfma_f32_16x16x32_bf16(qa, kb[n], (f32x4)0.f, 0,
                                                     0, 0);
    __builtin_amdgcn_s_setprio(0);

    #pragma unroll
    for (int j = 0; j < 4; ++j) {
      float p0 = exp2f(s[0][j]), p1 = exp2f(s[1][j]);
      float p2 = exp2f(s[2][j]), p3 = exp2f(s[3][j]);
      lpart[j] += (p0 + p1) + (p2 + p3);
      int prow = lhk * 4 + j;
      Ps[wid][prow][lrow] = (__bf16)p0;
      Ps[wid][prow][16 + lrow] = (__bf16)p1;
      Ps[wid][prow][32 + lrow] = (__bf16)p2;
      Ps[wid][prow][48 + lrow] = (__bf16)p3;
    }

    __builtin_amdgcn_s_setprio(1);
    #pragma unroll
    for (int ks = 0; ks < 2; ++ks) {
      bf16x8_t pa = *(const bf16x8_t*)&Ps[wid][lrow][ks * 32 + lhk * 8];
      #pragma unroll
      for (int dn = 0; dn < 2; ++dn) {
        bf16x8_t vbf =
            *(const bf16x8_t*)&Vs[buf][dn * 16 + lrow][ks * 32 + lhk * 8];
        o[dn] =
            __builtin_amdgcn_mfma_f32_16x16x32_bf16(pa, vbf, o[dn], 0, 0, 0);
      }
    }
    __builtin_amdgcn_s_setprio(0);

    if (t < 15) sstore(buf ^ 1);
    __syncthreads();
  }

  #pragma unroll
  for (int j = 0; j < 4; ++j) {
    float l = lpart[j];
    #pragma unroll
    for (int off = 1; off < 16; off <<= 1) l += __shfl_xor(l, off);
    float inv = 1.f / l;
    int row = q0 + wid * 16 + lhk * 4 + j;
    #pragma unroll
    for (int dn = 0; dn < 2; ++dn)
      O[(size_t)(bb * 1024 + row) * 512 + h * 32 + dn * 16 + lrow] =
          __builtin_bit_cast(unsigned short, (__bf16)(o[dn][j] * inv));
  }
}

extern "C" void kernel_launch(void* const* d_in, const int* in_sizes, int n_in,
                              void* d_out, int out_size, void* d_ws,
                              size_t ws_size, hipStream_t stream) {
  const float* x_in = (const float*)d_in[0];
  const float* gn_w = (const float*)d_in[1];
  const float* gn_b = (const float*)d_in[2];
  const float* pin_w = (const float*)d_in[3];
  const float* pin_b = (const float*)d_in[4];
  const float* pout_w = (const float*)d_in[5];
  const float* pout_b = (const float*)d_in[6];
  const float* ln1_w = (const float*)d_in[7];
  const float* ln1_b = (const float*)d_in[8];
  const float* wq = (const float*)d_in[9];
  const float* wk = (const float*)d_in[10];
  const float* wv = (const float*)d_in[11];
  const float* wo = (const float*)d_in[12];
  const float* bo = (const float*)d_in[13];
  const float* ln3_w = (const float*)d_in[14];
  const float* ln3_b = (const float*)d_in[15];
  const float* ff1_w = (const float*)d_in[16];
  const float* ff1_b = (const float*)d_in[17];
  const float* ff2_w = (const float*)d_in[18];
  const float* ff2_b = (const float*)d_in[19];

  char* wsb = (char*)d_ws;
  float* XTOK = (float*)wsb;                        // 8 MB residual fp32
  char* R = wsb + (8u << 20);                       // aliased region
  unsigned short* QKVb = (unsigned short*)R;        // 12 MB [4096][1536]
  unsigned short* G2b = (unsigned short*)R;         // 16 MB (alias QKV phase)
  float* gnsc = (float*)(R + (16u << 20));          // 8 KB
  float* gnsh = gnsc + 2048;                        // 8 KB
  unsigned short* XTb = (unsigned short*)(wsb + (32u << 20));    // 4 MB
  unsigned short* HXb = (unsigned short*)(wsb + (36u << 20));    // 4 MB
  unsigned short* Obf = (unsigned short*)(wsb + (40u << 20));    // 4 MB
  unsigned short* XTOKb = (unsigned short*)(wsb + (44u << 20));  // 4 MB
  unsigned short* W = (unsigned short*)(wsb + (48u << 20));
  const size_t S = 262144;  // 512*512
  unsigned short* pinT = W;
  unsigned short* poutT = W + S;
  unsigned short* wqkvT = W + 2 * S;               // 4 x [1536][512] interlvd
  unsigned short* woT = wqkvT + 12 * S;            // 4 x [512][512]
  unsigned short* ff1T = woT + 4 * S;              // 4 x [4096][512]
  unsigned short* ff2T = ff1T + 32 * S;            // 4 x [512][2048]

  // 1/sqrt(32) * log2(e) folded into wq -> exp2 in fattn
  const float qscale = 0.17677669529663687f * 1.4426950408889634f;

  gn_stats<<<64, 256, 0, stream>>>(x_in, gn_w, gn_b, gnsc, gnsh);

  CvtTab tab;
  int pre = 0;
  auto add = [&](int i, const float* src, unsigned short* dst, int rows,
                 int cols, int nmat, float sc, const float* rs,
                 const float* rsh, size_t mstr) {
    tab.e[i] = {src, dst, rs, rsh, rows, cols, nmat, pre, sc, mstr};
    pre += nmat * (rows / 64) * (cols / 32);
  };
  add(0, x_in, XTb, 512, 1024, 4, 1.f, gnsc, gnsh, 512 * 1024);
  add(1, pin_w, pinT, 512, 512, 1, 1.f, nullptr, nullptr, S);
  add(2, pout_w, poutT, 512, 512, 1, 1.f, nullptr, nullptr, S);
  add(3, wq, wqkvT, 512, 512, 4, qscale, nullptr, nullptr, 3 * S);
  add(4, wk, wqkvT + S, 512, 512, 4, 1.f, nullptr, nullptr, 3 * S);
  add(5, wv, wqkvT + 2 * S, 512, 512, 4, 1.f, nullptr, nullptr, 3 * S);
  add(6, wo, woT, 512, 512, 4, 1.f, nullptr, nullptr, S);
  add(7, ff1_w, ff1T, 512, 4096, 4, 1.f, nullptr, nullptr, 8 * S);
  add(8, ff2_w, ff2T, 2048, 512, 4, 1.f, nullptr, nullptr, 4 * S);
  cvt_all<<<pre, 256, 0, stream>>>(tab);

  // proj_in -> XTOK fp32 (TM=64: 2+ blocks/CU)
  mgemm<64, 64, 0><<<dim3(8, 64, 1), 256, 0, stream>>>(
      (const short*)XTb, 512, (const short*)pinT, XTOK, nullptr, 512, pin_b,
      nullptr, 512, 0);

  for (int l = 0; l < 4; ++l) {
    const short* wqkvT_l = (const short*)(wqkvT + (size_t)l * 3 * S);
    const short* woT_l = (const short*)(woT + (size_t)l * S);
    const short* ff1T_l = (const short*)(ff1T + (size_t)l * 8 * S);
    const short* ff2T_l = (const short*)(ff2T + (size_t)l * 4 * S);

    ln_kernel<<<1024, 256, 0, stream>>>(XTOK, ln1_w + l * 512, ln1_b + l * 512,
                                        HXb);
    // fused QKV: N=1536, TM=64/TN=128 -> 768 blocks (3/CU)
    mgemm<64, 128, 3><<<dim3(12, 64, 1), 256, 0, stream>>>(
        (const short*)HXb, 512, wqkvT_l, (float*)QKVb, nullptr, 1536, nullptr,
        nullptr, 512, 0);
    fattn_kernel<<<dim3(16, 16, 4), 256, 0, stream>>>(QKVb, Obf);
    mgemm<64, 64, 5><<<dim3(8, 64, 1), 256, 0, stream>>>(
        (const short*)Obf, 512, woT_l, XTOK, nullptr, 512, bo + l * 512, XTOK,
        512, 0);
    ln_kernel<<<1024, 256, 0, stream>>>(XTOK, ln3_w + l * 512, ln3_b + l * 512,
                                        HXb);
    // GEGLU ff1: TM=64 -> 48KB LDS, 3 blocks/CU, 2048 blocks
    mgemm<64, 64, 2><<<dim3(32, 64, 1), 256, 0, stream>>>(
        (const short*)HXb, 512, ff1T_l, nullptr, G2b, 2048, ff1_b + l * 4096,
        nullptr, 512, 2048);
    if (l < 3) {
      mgemm<64, 64, 5><<<dim3(8, 64, 1), 256, 0, stream>>>(
          (const short*)G2b, 2048, ff2T_l, XTOK, nullptr, 512, ff2_b + l * 512,
          XTOK, 2048, 0);
    } else {
      mgemm<64, 64, 1><<<dim3(8, 64, 1), 256, 0, stream>>>(
          (const short*)G2b, 2048, ff2T_l, XTOK, XTOKb, 512, ff2_b + l * 512,
          XTOK, 2048, 0);
    }
  }
  // proj_out fused with transpose + bias + input residual -> d_out
  mgemm<64, 64, 4><<<dim3(8, 64, 1), 256, 0, stream>>>(
      (const short*)XTOKb, 512, (const short*)poutT, (float*)d_out, nullptr,
      512, pout_b, x_in, 512, 0);
}

// Round 17
// 513.469 us; speedup vs baseline: 1.0242x; 1.0242x over previous
//
#include <hip/hip_runtime.h>
#include <math.h>

// B=4, C=512, n=1024 tokens, 16 heads x dh=32, 4 layers, GEGLU dff=2048.
// Residual stream fp32; GEMMs + attention bf16 MFMA (16x16x32), fp32 accum.
// Best-measured configuration (r15, 513.7us):
//   QKV TM=128/TN=128, ff1 TM=128/TN=64, narrow K=512 GEMMs TM=64.

typedef __bf16 bf16x8_t __attribute__((ext_vector_type(8)));
typedef float f32x4 __attribute__((ext_vector_type(4)));

__device__ __forceinline__ unsigned short f2bf(float f) {
  unsigned u = __float_as_uint(f);
  return (unsigned short)((u + 0x7FFFu + ((u >> 16) & 1u)) >> 16);
}
__device__ __forceinline__ float gelu_exact(float x) {
  return 0.5f * x * (1.f + erff(x * 0.70710678118654752440f));
}

// -------- GroupNorm stats: per (b,g) mean/rstd -> per-channel scale/shift ---
__global__ __launch_bounds__(256) void gn_stats(
    const float* __restrict__ X, const float* __restrict__ w,
    const float* __restrict__ b, float* __restrict__ sc,
    float* __restrict__ sh) {
  int blk = blockIdx.x;  // b*16 + g
  int g = blk & 15, bb = blk >> 4;
  const float4* x4 = (const float4*)(X + (size_t)blk * 32768);
  int tid = threadIdx.x;
  float sum = 0.f, sq = 0.f;
  for (int i = tid; i < 8192; i += 256) {
    float4 v = x4[i];
    sum += v.x + v.y + v.z + v.w;
    sq += v.x * v.x + v.y * v.y + v.z * v.z + v.w * v.w;
  }
  #pragma unroll
  for (int off = 32; off; off >>= 1) {
    sum += __shfl_xor(sum, off);
    sq += __shfl_xor(sq, off);
  }
  __shared__ float s0[4], s1[4];
  int wid = tid >> 6, lane = tid & 63;
  if (lane == 0) { s0[wid] = sum; s1[wid] = sq; }
  __syncthreads();
  sum = s0[0] + s0[1] + s0[2] + s0[3];
  sq = s1[0] + s1[1] + s1[2] + s1[3];
  float mean = sum * (1.f / 32768.f);
  float var = sq * (1.f / 32768.f) - mean * mean;
  float rstd = rsqrtf(var + 1e-6f);
  if (tid < 32) {
    int ch = g * 32 + tid;
    float s_ = rstd * w[ch];
    sc[bb * 512 + ch] = s_;
    sh[bb * 512 + ch] = b[ch] - mean * s_;
  }
}

// ------- batched transpose+convert: fp32 [rows][cols] -> bf16 [cols][rows] --
struct CvtEnt {
  const float* src; unsigned short* dst;
  const float* rs; const float* rsh;
  int rows, cols, nmat, pre; float scale; size_t mstr;
};
struct CvtTab { CvtEnt e[9]; };

__global__ __launch_bounds__(256) void cvt_all(CvtTab tab) {
  __shared__ __bf16 t[32][72];
  int blk = blockIdx.x;
  int ei = 0;
  #pragma unroll
  for (int i = 1; i < 9; ++i)
    if (blk >= tab.e[i].pre) ei = i;
  const CvtEnt E = tab.e[ei];
  int local = blk - E.pre;
  int tcx = E.cols >> 5, trx = E.rows >> 6;
  int tpm = tcx * trx;
  int mat = local / tpm, tt = local - mat * tpm;
  int r0 = (tt / tcx) << 6, c0 = (tt % tcx) << 5;
  const float* sp = E.src + (size_t)mat * E.rows * E.cols;
  unsigned short* dp = E.dst + (size_t)mat * E.mstr;
  int tid = threadIdx.x;
  int r = tid >> 2, cq = (tid & 3) << 3;
  float s_ = E.scale, h_ = 0.f;
  if (E.rs) {
    s_ = E.rs[(size_t)mat * E.rows + r0 + r];
    h_ = E.rsh[(size_t)mat * E.rows + r0 + r];
  }
  const float* rowp = sp + (size_t)(r0 + r) * E.cols + c0 + cq;
  float4 a = *(const float4*)rowp;
  float4 b = *(const float4*)(rowp + 4);
  t[cq + 0][r] = (__bf16)(a.x * s_ + h_);
  t[cq + 1][r] = (__bf16)(a.y * s_ + h_);
  t[cq + 2][r] = (__bf16)(a.z * s_ + h_);
  t[cq + 3][r] = (__bf16)(a.w * s_ + h_);
  t[cq + 4][r] = (__bf16)(b.x * s_ + h_);
  t[cq + 5][r] = (__bf16)(b.y * s_ + h_);
  t[cq + 6][r] = (__bf16)(b.z * s_ + h_);
  t[cq + 7][r] = (__bf16)(b.w * s_ + h_);
  __syncthreads();
  int c = tid >> 3, r8 = (tid & 7) << 3;
  bf16x8_t v = *(const bf16x8_t*)&t[c][r8];
  *(bf16x8_t*)&dp[(size_t)(c0 + c) * E.rows + r0 + r8] = v;
}

// -------- LayerNorm C=512: wave per row, 4 rows/block, fp32->bf16 ---------
__global__ __launch_bounds__(256) void ln_kernel(
    const float* __restrict__ X, const float* __restrict__ w,
    const float* __restrict__ b, unsigned short* __restrict__ Y) {
  int row = blockIdx.x * 4 + (threadIdx.x >> 6);
  int lane = threadIdx.x & 63;
  const float4* xr = (const float4*)(X + (size_t)row * 512);
  float4 v0 = xr[lane];
  float4 v1 = xr[lane + 64];
  float sum = v0.x + v0.y + v0.z + v0.w + v1.x + v1.y + v1.z + v1.w;
  float sq = v0.x * v0.x + v0.y * v0.y + v0.z * v0.z + v0.w * v0.w +
             v1.x * v1.x + v1.y * v1.y + v1.z * v1.z + v1.w * v1.w;
  #pragma unroll
  for (int off = 32; off; off >>= 1) {
    sum += __shfl_xor(sum, off);
    sq += __shfl_xor(sq, off);
  }
  float mean = sum * (1.f / 512.f);
  float var = sq * (1.f / 512.f) - mean * mean;
  float rstd = rsqrtf(var + 1e-5f);
  unsigned short* yr = Y + (size_t)row * 512;
  int c0 = lane * 4, c1 = lane * 4 + 256;
  const float4 w0 = *(const float4*)&w[c0], b0v = *(const float4*)&b[c0];
  const float4 w1 = *(const float4*)&w[c1], b1v = *(const float4*)&b[c1];
  unsigned p0 = (unsigned)f2bf((v0.x - mean) * rstd * w0.x + b0v.x) |
                ((unsigned)f2bf((v0.y - mean) * rstd * w0.y + b0v.y) << 16);
  unsigned p1 = (unsigned)f2bf((v0.z - mean) * rstd * w0.z + b0v.z) |
                ((unsigned)f2bf((v0.w - mean) * rstd * w0.w + b0v.w) << 16);
  unsigned p2 = (unsigned)f2bf((v1.x - mean) * rstd * w1.x + b1v.x) |
                ((unsigned)f2bf((v1.y - mean) * rstd * w1.y + b1v.y) << 16);
  unsigned p3 = (unsigned)f2bf((v1.z - mean) * rstd * w1.z + b1v.z) |
                ((unsigned)f2bf((v1.w - mean) * rstd * w1.w + b1v.w) << 16);
  uint2 q0 = {p0, p1}, q1 = {p2, p3};
  *(uint2*)&yr[c0] = q0;
  *(uint2*)&yr[c1] = q1;
}

// ---------------- bf16 MFMA GEMM (16x16x32, XCD-swizzled, reg-staged) ------
// A [M][lda] bf16 row-major; B^T [N][K] bf16 row-major.
// 256 thr = 4 waves (2x2), tile TM x TN, wave tile (TM/2)x(TN/2), BK=64.
// MODE 0: C_f32 = acc (+bias).
// MODE 1: v = acc+bias+resid -> C_f32 and Cb_bf16 (LDS-repacked write).
// MODE 2: GEGLU: Cb_bf16 = (acc+bias[col]) * gelu(acc2+bias[ggoff+col]).
// MODE 3: bf16 = acc -> C reinterpreted as bf16 (LDS-repacked write).
// MODE 4: out[b][col][n] = acc + bias[col] + resid[b][col][n] (rows = tokens).
// MODE 5: C_f32 = acc+bias+resid (no bf16 mirror).
template <int TM, int TN, int MODE>
__global__ __launch_bounds__(256) void mgemm(
    const short* __restrict__ A, int lda, const short* __restrict__ B0,
    float* C0, unsigned short* Cb, int ldc,
    const float* __restrict__ bias, const float* resid, int K, int ggoff) {
  constexpr int WM = TM / 2, WN = TN / 2, MF = WM / 16, NF = WN / 16;
  constexpr int ASL = TM / 32;
  constexpr int BSL = TN / 32;
  __shared__ short As[2][TM][64];
  __shared__ short Bs[2][TN][64];
  __shared__ short Bs2[MODE == 2 ? 2 : 1][MODE == 2 ? TN : 1][64];

  // ---- XCD-band swizzle (requires gridDim.y % 8 == 0) ----
  int flat = (blockIdx.z * gridDim.y + blockIdx.y) * gridDim.x + blockIdx.x;
  int xcd = flat & 7;
  int pos = flat >> 3;
  int bandH = gridDim.y >> 3;
  int m_loc = pos % bandH;
  int bn_i = pos / bandH;
  int bm = (xcd * bandH + m_loc) * TM;
  int bn = bn_i * TN;

  const short* B = B0;
  float* C = C0;
  const short* Bg = (MODE == 2) ? B0 + (size_t)ggoff * K : nullptr;
  unsigned short* Cbw = (MODE == 3) ? (unsigned short*)C : Cb;

  int tid = threadIdx.x;

  f32x4 acc[MF][NF];
  f32x4 acc2[MODE == 2 ? MF : 1][MODE == 2 ? NF : 1];
  #pragma unroll
  for (int m = 0; m < MF; ++m)
    #pragma unroll
    for (int n = 0; n < NF; ++n) {
      acc[m][n] = (f32x4)0.f;
      if (MODE == 2) acc2[m][n] = (f32x4)0.f;
    }

  int wid = tid >> 6, lane = tid & 63;
  int wr = wid >> 1, wc = wid & 1;
  int lrow = lane & 15, lhk = lane >> 4;

  bf16x8_t ra[ASL], rb[BSL], rb2[MODE == 2 ? BSL : 1];

  auto load_regs = [&](int k0) {
    #pragma unroll
    for (int i = 0; i < ASL; ++i) {
      int slot = tid + i * 256, r = slot >> 3, s = slot & 7;
      ra[i] = *(const bf16x8_t*)(A + (size_t)(bm + r) * lda + k0 + s * 8);
    }
    #pragma unroll
    for (int i = 0; i < BSL; ++i) {
      int slot = tid + i * 256, r = slot >> 3, s = slot & 7;
      rb[i] = *(const bf16x8_t*)(B + (size_t)(bn + r) * K + k0 + s * 8);
      if (MODE == 2)
        rb2[i] = *(const bf16x8_t*)(Bg + (size_t)(bn + r) * K + k0 + s * 8);
    }
  };
  auto store_lds = [&](int bufi) {
    #pragma unroll
    for (int i = 0; i < ASL; ++i) {
      int slot = tid + i * 256, r = slot >> 3, s = slot & 7;
      *(bf16x8_t*)&As[bufi][r][(s ^ (r & 7)) * 8] = ra[i];
    }
    #pragma unroll
    for (int i = 0; i < BSL; ++i) {
      int slot = tid + i * 256, r = slot >> 3, s = slot & 7;
      *(bf16x8_t*)&Bs[bufi][r][(s ^ (r & 7)) * 8] = rb[i];
      if (MODE == 2) *(bf16x8_t*)&Bs2[bufi][r][(s ^ (r & 7)) * 8] = rb2[i];
    }
  };
  auto compute = [&](int bufi) {
    bf16x8_t af[2][MF], bfr[2][NF], bf2[MODE == 2 ? 2 : 1][MODE == 2 ? NF : 1];
    #pragma unroll
    for (int ks = 0; ks < 2; ++ks) {
      int sl = ks * 4 + lhk;
      int ph = (sl ^ (lrow & 7)) * 8;
      #pragma unroll
      for (int m = 0; m < MF; ++m)
        af[ks][m] = *(const bf16x8_t*)&As[bufi][wr * WM + m * 16 + lrow][ph];
      #pragma unroll
      for (int n = 0; n < NF; ++n) {
        bfr[ks][n] = *(const bf16x8_t*)&Bs[bufi][wc * WN + n * 16 + lrow][ph];
        if (MODE == 2)
          bf2[ks][n] = *(const bf16x8_t*)&Bs2[bufi][wc * WN + n * 16 + lrow][ph];
      }
    }
    #pragma unroll
    for (int ks = 0; ks < 2; ++ks)
      #pragma unroll
      for (int m = 0; m < MF; ++m)
        #pragma unroll
        for (int n = 0; n < NF; ++n) {
          acc[m][n] = __builtin_amdgcn_mfma_f32_16x16x32_bf16(
              af[ks][m], bfr[ks][n], acc[m][n], 0, 0, 0);
          if (MODE == 2)
            acc2[m][n] = __builtin_amdgcn_mfma_f32_16x16x32_bf16(
                af[ks][m], bf2[ks][n], acc2[m][n], 0, 0, 0);
        }
  };

  int ns = K >> 6;
  load_regs(0);
  store_lds(0);
  __syncthreads();
  int buf = 0;
  for (int t = 0; t < ns; ++t) {
    bool more = (t + 1 < ns);
    if (more) load_regs((t + 1) << 6);  // issue early (T14)
    compute(buf);
    if (more) store_lds(buf ^ 1);       // write late
    __syncthreads();
    buf ^= 1;
  }

  int row0 = bm + wr * WM + lhk * 4;
  int col0 = bn + wc * WN + lrow;
  // LDS repack buffer for coalesced bf16 output (reuses As)
  unsigned short (*Lb)[TN] = (unsigned short(*)[TN])(&As[0][0][0]);
  #pragma unroll
  for (int m = 0; m < MF; ++m) {
    #pragma unroll
    for (int n = 0; n < NF; ++n) {
      int col = col0 + n * 16;
      int rl0 = wr * WM + m * 16 + lhk * 4;  // row within tile
      int cl = wc * WN + n * 16 + lrow;      // col within tile
      if (MODE == 0) {
        float bv = bias ? bias[col] : 0.f;
        #pragma unroll
        for (int j = 0; j < 4; ++j) {
          int row = row0 + m * 16 + j;
          C[(size_t)row * ldc + col] = acc[m][n][j] + bv;
        }
      } else if (MODE == 1) {
        float bv = bias[col];
        #pragma unroll
        for (int j = 0; j < 4; ++j) {
          int row = row0 + m * 16 + j;
          float v = acc[m][n][j] + bv + resid[(size_t)row * ldc + col];
          C[(size_t)row * ldc + col] = v;
          Lb[rl0 + j][cl] = f2bf(v);
        }
      } else if (MODE == 2) {
        float ba = bias[col], bg = bias[ggoff + col];
        #pragma unroll
        for (int j = 0; j < 4; ++j) {
          float a = acc[m][n][j] + ba;
          float g = acc2[m][n][j] + bg;
          Lb[rl0 + j][cl] = f2bf(a * gelu_exact(g));
        }
      } else if (MODE == 3) {
        #pragma unroll
        for (int j = 0; j < 4; ++j) Lb[rl0 + j][cl] = f2bf(acc[m][n][j]);
      } else if (MODE == 4) {
        // transposed write + bias + residual, rows = tokens
        float bv = bias[col];
        int row = row0 + m * 16;
        int b_ = row >> 10, n0 = row & 1023;
        size_t oidx = ((size_t)b_ * 512 + col) * 1024 + n0;
        float4 xi = *(const float4*)&resid[oidx];
        float4 ov = {acc[m][n][0] + bv + xi.x, acc[m][n][1] + bv + xi.y,
                     acc[m][n][2] + bv + xi.z, acc[m][n][3] + bv + xi.w};
        *(float4*)&C[oidx] = ov;
      } else {
        // MODE 5: fp32 bias+resid only
        float bv = bias[col];
        #pragma unroll
        for (int j = 0; j < 4; ++j) {
          int row = row0 + m * 16 + j;
          C[(size_t)row * ldc + col] =
              acc[m][n][j] + bv + resid[(size_t)row * ldc + col];
        }
      }
    }
  }
  if (MODE == 1 || MODE == 2 || MODE == 3) {
    __syncthreads();
    constexpr int CQ = TN / 8;
    #pragma unroll
    for (int i = 0; i < TM * TN / 8 / 256; ++i) {
      int slot = tid + i * 256;
      int r = slot / CQ, cq = (slot % CQ) * 8;
      *(bf16x8_t*)&Cbw[(size_t)(bm + r) * ldc + bn + cq] =
          *(const bf16x8_t*)&Lb[r][cq];
    }
  }
}

// ---------------- MFMA flash attention (QT=64, dbuf K/V, 1 barrier/tile) ---
// Block = (q-tile of 64, head, batch); 256 thr = 4 waves, wave owns 16 q.
// QKV packed [4096][1536] (q|k|v), Q pre-scaled by log2(e)/sqrt(32).
// Pitches (empirically best, r8): Ks 40, Vs 68, Ps 68.
__global__ __launch_bounds__(256) void fattn_kernel(
    const unsigned short* __restrict__ QKV, unsigned short* __restrict__ O) {
  constexpr int KT = 64, LDQ = 1536;
  __shared__ __bf16 Ks[2][KT][40];
  __shared__ __bf16 Vs[2][32][68];
  __shared__ __bf16 Ps[4][16][68];

  int h = blockIdx.y, bb = blockIdx.z;
  int q0 = blockIdx.x * 64;
  int tid = threadIdx.x;
  int wid = tid >> 6, lane = tid & 63;
  int lrow = lane & 15, lhk = lane >> 4;

  const unsigned short* Qb = QKV + (size_t)bb * 1024 * LDQ + h * 32;
  const unsigned short* Kb = Qb + 512;
  const unsigned short* Vb = Qb + 1024;

  bf16x8_t qa = *(const bf16x8_t*)(
      Qb + (size_t)(q0 + wid * 16 + lrow) * LDQ + lhk * 8);

  int kr = tid >> 2, kp = tid & 3;
  int vk = tid & 63, vd0 = (tid >> 6) * 8;

  bf16x8_t kreg, vreg;
  auto gload = [&](int kt) {
    kreg = *(const bf16x8_t*)(Kb + (size_t)(kt + kr) * LDQ + kp * 8);
    vreg = *(const bf16x8_t*)(Vb + (size_t)(kt + vk) * LDQ + vd0);
  };
  auto sstore = [&](int bufi) {
    *(bf16x8_t*)&Ks[bufi][kr][kp * 8] = kreg;
    #pragma unroll
    for (int i = 0; i < 8; ++i) Vs[bufi][vd0 + i][vk] = vreg[i];
  };

  f32x4 o[2];
  float lpart[4];
  o[0] = (f32x4)0.f;
  o[1] = (f32x4)0.f;
  #pragma unroll
  for (int j = 0; j < 4; ++j) lpart[j] = 0.f;

  gload(0);
  sstore(0);
  __syncthreads();
  for (int t = 0; t < 16; ++t) {
    int buf = t & 1;
    if (t < 15) gload((t + 1) * KT);  // prefetch next tile into regs (T14)

    bf16x8_t kb[4];
    #pragma unroll
    for (int n = 0; n < 4; ++n)
      kb[n] = *(const bf16x8_t*)&Ks[buf][n * 16 + lrow][lhk * 8];
    f32x4 s[4];
    __builtin_amdgcn_s_setprio(1);
    #pragma unroll
    for (int n = 0; n < 4; ++n)
      s[n] = __builtin_amdgcn_mfma_f32_16x16x32_bf16(qa, kb[n], (f32x4)0.f, 0,
                                                     0, 0);
    __builtin_amdgcn_s_setprio(0);

    #pragma unroll
    for (int j = 0; j < 4; ++j) {
      float p0 = exp2f(s[0][j]), p1 = exp2f(s[1][j]);
      float p2 = exp2f(s[2][j]), p3 = exp2f(s[3][j]);
      lpart[j] += (p0 + p1) + (p2 + p3);
      int prow = lhk * 4 + j;
      Ps[wid][prow][lrow] = (__bf16)p0;
      Ps[wid][prow][16 + lrow] = (__bf16)p1;
      Ps[wid][prow][32 + lrow] = (__bf16)p2;
      Ps[wid][prow][48 + lrow] = (__bf16)p3;
    }

    __builtin_amdgcn_s_setprio(1);
    #pragma unroll
    for (int ks = 0; ks < 2; ++ks) {
      bf16x8_t pa = *(const bf16x8_t*)&Ps[wid][lrow][ks * 32 + lhk * 8];
      #pragma unroll
      for (int dn = 0; dn < 2; ++dn) {
        bf16x8_t vbf =
            *(const bf16x8_t*)&Vs[buf][dn * 16 + lrow][ks * 32 + lhk * 8];
        o[dn] =
            __builtin_amdgcn_mfma_f32_16x16x32_bf16(pa, vbf, o[dn], 0, 0, 0);
      }
    }
    __builtin_amdgcn_s_setprio(0);

    if (t < 15) sstore(buf ^ 1);
    __syncthreads();
  }

  #pragma unroll
  for (int j = 0; j < 4; ++j) {
    float l = lpart[j];
    #pragma unroll
    for (int off = 1; off < 16; off <<= 1) l += __shfl_xor(l, off);
    float inv = 1.f / l;
    int row = q0 + wid * 16 + lhk * 4 + j;
    #pragma unroll
    for (int dn = 0; dn < 2; ++dn)
      O[(size_t)(bb * 1024 + row) * 512 + h * 32 + dn * 16 + lrow] =
          __builtin_bit_cast(unsigned short, (__bf16)(o[dn][j] * inv));
  }
}

extern "C" void kernel_launch(void* const* d_in, const int* in_sizes, int n_in,
                              void* d_out, int out_size, void* d_ws,
                              size_t ws_size, hipStream_t stream) {
  const float* x_in = (const float*)d_in[0];
  const float* gn_w = (const float*)d_in[1];
  const float* gn_b = (const float*)d_in[2];
  const float* pin_w = (const float*)d_in[3];
  const float* pin_b = (const float*)d_in[4];
  const float* pout_w = (const float*)d_in[5];
  const float* pout_b = (const float*)d_in[6];
  const float* ln1_w = (const float*)d_in[7];
  const float* ln1_b = (const float*)d_in[8];
  const float* wq = (const float*)d_in[9];
  const float* wk = (const float*)d_in[10];
  const float* wv = (const float*)d_in[11];
  const float* wo = (const float*)d_in[12];
  const float* bo = (const float*)d_in[13];
  const float* ln3_w = (const float*)d_in[14];
  const float* ln3_b = (const float*)d_in[15];
  const float* ff1_w = (const float*)d_in[16];
  const float* ff1_b = (const float*)d_in[17];
  const float* ff2_w = (const float*)d_in[18];
  const float* ff2_b = (const float*)d_in[19];

  char* wsb = (char*)d_ws;
  float* XTOK = (float*)wsb;                        // 8 MB residual fp32
  char* R = wsb + (8u << 20);                       // aliased region
  unsigned short* QKVb = (unsigned short*)R;        // 12 MB [4096][1536]
  unsigned short* G2b = (unsigned short*)R;         // 16 MB (alias QKV phase)
  float* gnsc = (float*)(R + (16u << 20));          // 8 KB
  float* gnsh = gnsc + 2048;                        // 8 KB
  unsigned short* XTb = (unsigned short*)(wsb + (32u << 20));    // 4 MB
  unsigned short* HXb = (unsigned short*)(wsb + (36u << 20));    // 4 MB
  unsigned short* Obf = (unsigned short*)(wsb + (40u << 20));    // 4 MB
  unsigned short* XTOKb = (unsigned short*)(wsb + (44u << 20));  // 4 MB
  unsigned short* W = (unsigned short*)(wsb + (48u << 20));
  const size_t S = 262144;  // 512*512
  unsigned short* pinT = W;
  unsigned short* poutT = W + S;
  unsigned short* wqkvT = W + 2 * S;               // 4 x [1536][512] interlvd
  unsigned short* woT = wqkvT + 12 * S;            // 4 x [512][512]
  unsigned short* ff1T = woT + 4 * S;              // 4 x [4096][512]
  unsigned short* ff2T = ff1T + 32 * S;            // 4 x [512][2048]

  // 1/sqrt(32) * log2(e) folded into wq -> exp2 in fattn
  const float qscale = 0.17677669529663687f * 1.4426950408889634f;

  gn_stats<<<64, 256, 0, stream>>>(x_in, gn_w, gn_b, gnsc, gnsh);

  CvtTab tab;
  int pre = 0;
  auto add = [&](int i, const float* src, unsigned short* dst, int rows,
                 int cols, int nmat, float sc, const float* rs,
                 const float* rsh, size_t mstr) {
    tab.e[i] = {src, dst, rs, rsh, rows, cols, nmat, pre, sc, mstr};
    pre += nmat * (rows / 64) * (cols / 32);
  };
  add(0, x_in, XTb, 512, 1024, 4, 1.f, gnsc, gnsh, 512 * 1024);
  add(1, pin_w, pinT, 512, 512, 1, 1.f, nullptr, nullptr, S);
  add(2, pout_w, poutT, 512, 512, 1, 1.f, nullptr, nullptr, S);
  add(3, wq, wqkvT, 512, 512, 4, qscale, nullptr, nullptr, 3 * S);
  add(4, wk, wqkvT + S, 512, 512, 4, 1.f, nullptr, nullptr, 3 * S);
  add(5, wv, wqkvT + 2 * S, 512, 512, 4, 1.f, nullptr, nullptr, 3 * S);
  add(6, wo, woT, 512, 512, 4, 1.f, nullptr, nullptr, S);
  add(7, ff1_w, ff1T, 512, 4096, 4, 1.f, nullptr, nullptr, 8 * S);
  add(8, ff2_w, ff2T, 2048, 512, 4, 1.f, nullptr, nullptr, 4 * S);
  cvt_all<<<pre, 256, 0, stream>>>(tab);

  // proj_in -> XTOK fp32 (TM=64: 2 blocks/CU)
  mgemm<64, 64, 0><<<dim3(8, 64, 1), 256, 0, stream>>>(
      (const short*)XTb, 512, (const short*)pinT, XTOK, nullptr, 512, pin_b,
      nullptr, 512, 0);

  for (int l = 0; l < 4; ++l) {
    const short* wqkvT_l = (const short*)(wqkvT + (size_t)l * 3 * S);
    const short* woT_l = (const short*)(woT + (size_t)l * S);
    const short* ff1T_l = (const short*)(ff1T + (size_t)l * 8 * S);
    const short* ff2T_l = (const short*)(ff2T + (size_t)l * 4 * S);

    ln_kernel<<<1024, 256, 0, stream>>>(XTOK, ln1_w + l * 512, ln1_b + l * 512,
                                        HXb);
    // fused QKV: N=1536, TM=128/TN=128 -> 384 blocks (r15 best)
    mgemm<128, 128, 3><<<dim3(12, 32, 1), 256, 0, stream>>>(
        (const short*)HXb, 512, wqkvT_l, (float*)QKVb, nullptr, 1536, nullptr,
        nullptr, 512, 0);
    fattn_kernel<<<dim3(16, 16, 4), 256, 0, stream>>>(QKVb, Obf);
    mgemm<64, 64, 5><<<dim3(8, 64, 1), 256, 0, stream>>>(
        (const short*)Obf, 512, woT_l, XTOK, nullptr, 512, bo + l * 512, XTOK,
        512, 0);
    ln_kernel<<<1024, 256, 0, stream>>>(XTOK, ln3_w + l * 512, ln3_b + l * 512,
                                        HXb);
    // GEGLU ff1: TM=128/TN=64 (r15 best: B-panel reuse)
    mgemm<128, 64, 2><<<dim3(32, 32, 1), 256, 0, stream>>>(
        (const short*)HXb, 512, ff1T_l, nullptr, G2b, 2048, ff1_b + l * 4096,
        nullptr, 512, 2048);
    if (l < 3) {
      mgemm<64, 64, 5><<<dim3(8, 64, 1), 256, 0, stream>>>(
          (const short*)G2b, 2048, ff2T_l, XTOK, nullptr, 512, ff2_b + l * 512,
          XTOK, 2048, 0);
    } else {
      mgemm<64, 64, 1><<<dim3(8, 64, 1), 256, 0, stream>>>(
          (const short*)G2b, 2048, ff2T_l, XTOK, XTOKb, 512, ff2_b + l * 512,
          XTOK, 2048, 0);
    }
  }
  // proj_out fused with transpose + bias + input residual -> d_out
  mgemm<64, 64, 4><<<dim3(8, 64, 1), 256, 0, stream>>>(
      (const short*)XTOKb, 512, (const short*)poutT, (float*)d_out, nullptr,
      512, pout_b, x_in, 512, 0);
}